// Round 1
// baseline (3281.627 us; speedup 1.0000x reference)
//
#include <hip/hip_runtime.h>
#include <hip/hip_bf16.h>

#define NN 80000
#define EE 320000
#define ET 400000   // EE + NN self loops
#define BB 3200
#define LL 5

typedef __attribute__((ext_vector_type(8))) short bf16x8;
typedef __attribute__((ext_vector_type(4))) float f32x4;

// ---------------- preprocessing ----------------

__global__ void k_deg(const int* ei, int* deg) {
    int e = blockIdx.x * 256 + threadIdx.x;
    if (e >= ET) return;
    int d = (e < EE) ? ei[EE + e] : (e - EE);
    atomicAdd(&deg[d], 1);
}

__global__ void k_scan(const int* deg, int* row_start, int* cursor, int n) {
    __shared__ int sh[1024];
    __shared__ int carry;
    int t = threadIdx.x;
    if (t == 0) carry = 0;
    __syncthreads();
    for (int base = 0; base < n; base += 1024) {
        int v = (base + t < n) ? deg[base + t] : 0;
        sh[t] = v;
        __syncthreads();
        for (int off = 1; off < 1024; off <<= 1) {
            int x = (t >= off) ? sh[t - off] : 0;
            __syncthreads();
            sh[t] += x;
            __syncthreads();
        }
        int exc = sh[t] - v;
        int c = carry;
        if (base + t < n) { row_start[base + t] = c + exc; cursor[base + t] = c + exc; }
        __syncthreads();
        if (t == 1023) carry = c + sh[1023];
        __syncthreads();
    }
    if (t == 0) row_start[n] = carry;
}

__global__ void k_fill(const int* ei, const int* ea, int* cursor, int* eid, int* combo) {
    int e = blockIdx.x * 256 + threadIdx.x;
    if (e >= ET) return;
    int d = (e < EE) ? ei[EE + e] : (e - EE);
    int p = atomicAdd(&cursor[d], 1);
    eid[p] = e;
    int c;
    if (e < EE) c = ea[e * 3 + 0] * 12 + ea[e * 3 + 1] * 2 + ea[e * 3 + 2];
    else        c = 22 * 12;   // self loop attr [22,0,0]
    combo[e] = c;
}

__global__ void k_ecomb(const float* e1, const float* e2, const float* e3, float* ec) {
    int l = blockIdx.x / 300, c = blockIdx.x % 300, d = threadIdx.x;
    int a0 = c / 12, a1 = (c / 2) % 6, a2 = c & 1;
    ec[(size_t)(l * 300 + c) * 256 + d] =
        e1[(size_t)(l * 25 + a0) * 256 + d] +
        e2[(size_t)(l * 6 + a1) * 256 + d] +
        e3[(size_t)(l * 2 + a2) * 256 + d];
}

// W1: [L][256][512] -> W1t: [L][512][256] bf16
__global__ void k_w1t(const float* W, __hip_bfloat16* Wt) {
    int i = blockIdx.x * 256 + threadIdx.x;
    if (i >= LL * 512 * 256) return;
    int l = i / (512 * 256); int r = i % (512 * 256); int n = r / 256; int k = r % 256;
    Wt[i] = __float2bfloat16(W[(size_t)(l * 256 + k) * 512 + n]);
}
// W2: [L][512][256] -> W2t: [L][256][512] bf16
__global__ void k_w2t(const float* W, __hip_bfloat16* Wt) {
    int i = blockIdx.x * 256 + threadIdx.x;
    if (i >= LL * 256 * 512) return;
    int l = i / (256 * 512); int r = i % (256 * 512); int n = r / 512; int k = r % 512;
    Wt[i] = __float2bfloat16(W[(size_t)(l * 512 + k) * 256 + n]);
}

__global__ void k_nodeemb(const int* x, const float* emb, __hip_bfloat16* h) {
    const int offs[9] = {0, 121, 129, 141, 156, 166, 175, 182, 185};
    int i = blockIdx.x; int d = threadIdx.x;
    float acc = 0.f;
#pragma unroll
    for (int c = 0; c < 9; c++) {
        int idx = x[i * 9 + c] + offs[c];
        acc += emb[(size_t)idx * 256 + d];
    }
    h[(size_t)i * 256 + d] = __float2bfloat16(acc);
}

// ---------------- per-layer ----------------

__global__ void k_aggr(const __hip_bfloat16* h, const float* ecomb_l, const int* row_start,
                       const int* eid, const int* combo, const int* ei_src,
                       __hip_bfloat16* aggrB) {
    int v = blockIdx.x; int d = threadIdx.x;
    int s0 = row_start[v], s1 = row_start[v + 1];
    float acc = 0.f;
    for (int p = s0; p < s1; p++) {
        int e = eid[p];
        int s = (e < EE) ? ei_src[e] : (e - EE);
        int c = combo[e];
        acc += __bfloat162float(h[(size_t)s * 256 + d]) + ecomb_l[(size_t)c * 256 + d];
    }
    aggrB[(size_t)v * 256 + d] = __float2bfloat16(acc);
}

// C[M,Nn] = act( A[M,K](bf16) * Wt[Nn,K]^T (bf16) + bias ), tile 128x64, 4 waves
template<int K, bool RELU, bool OUTBF>
__global__ __launch_bounds__(256) void k_gemm(const __hip_bfloat16* A, const __hip_bfloat16* Wt,
                                              const float* bias, void* out, int Nn) {
    int wave = threadIdx.x >> 6, lane = threadIdx.x & 63;
    int rowBase = blockIdx.x * 128 + wave * 32;
    int colBase = blockIdx.y * 64;
    int lr = lane & 15, lk = lane >> 4;
    const short* Ap = (const short*)A;
    const short* Wp = (const short*)Wt;
    f32x4 acc[2][4] = {};
    for (int k0 = 0; k0 < K; k0 += 32) {
        bf16x8 a[2], b[4];
#pragma unroll
        for (int m = 0; m < 2; m++)
            a[m] = *(const bf16x8*)(Ap + (size_t)(rowBase + m * 16 + lr) * K + k0 + lk * 8);
#pragma unroll
        for (int n = 0; n < 4; n++)
            b[n] = *(const bf16x8*)(Wp + (size_t)(colBase + n * 16 + lr) * K + k0 + lk * 8);
#pragma unroll
        for (int m = 0; m < 2; m++)
#pragma unroll
            for (int n = 0; n < 4; n++)
                acc[m][n] = __builtin_amdgcn_mfma_f32_16x16x32_bf16(a[m], b[n], acc[m][n], 0, 0, 0);
    }
#pragma unroll
    for (int m = 0; m < 2; m++)
#pragma unroll
        for (int n = 0; n < 4; n++)
#pragma unroll
            for (int j = 0; j < 4; j++) {
                int r = rowBase + m * 16 + lk * 4 + j;
                int cdx = colBase + n * 16 + lr;
                float v = acc[m][n][j] + bias[cdx];
                if (RELU) v = fmaxf(v, 0.f);
                if (OUTBF) ((__hip_bfloat16*)out)[(size_t)r * Nn + cdx] = __float2bfloat16(v);
                else       ((float*)out)[(size_t)r * Nn + cdx] = v;
            }
}

__global__ void k_bn1(const float* h2, float* part, int rowsPerBlk) {
    int d = threadIdx.x; int b = blockIdx.x;
    int r0 = b * rowsPerBlk, r1 = r0 + rowsPerBlk;
    if (r1 > NN) r1 = NN;
    float s = 0.f, s2 = 0.f;
    for (int r = r0; r < r1; r++) {
        float v = h2[(size_t)r * 256 + d];
        s += v; s2 += v * v;
    }
    part[(size_t)(b * 256 + d) * 2]     = s;
    part[(size_t)(b * 256 + d) * 2 + 1] = s2;
}

__global__ void k_bn2(const float* part, const float* g, const float* bta, float* stat, int nb) {
    int d = threadIdx.x;
    float s = 0.f, s2 = 0.f;
    for (int b = 0; b < nb; b++) {
        s  += part[(size_t)(b * 256 + d) * 2];
        s2 += part[(size_t)(b * 256 + d) * 2 + 1];
    }
    float mean = s / NN;
    float var = s2 / NN - mean * mean;
    float sc = rsqrtf(var + 1e-5f) * g[d];
    stat[d] = sc;
    stat[256 + d] = bta[d] - mean * sc;
}

__global__ void k_bnapply(const float* h2, const float* stat, __hip_bfloat16* h, int relu) {
    int i = blockIdx.x * 256 + threadIdx.x;   // over NN*256
    int d = i & 255;
    float v = h2[i] * stat[d] + stat[256 + d];
    if (relu) v = fmaxf(v, 0.f);
    h[i] = __float2bfloat16(v);
}

// ---------------- head ----------------

__global__ __launch_bounds__(128) void k_head(const __hip_bfloat16* h,
        const float* HW1, const float* Hb1, const float* HW2, const float* Hb2,
        const float* HW3, const float* Hb3, float* out) {
    __shared__ float row[256], z1[128], z2[128];
    int g = blockIdx.x; int t = threadIdx.x;
    size_t node = (size_t)g * 25 + 24;
    row[t]       = __bfloat162float(h[node * 256 + t]);
    row[t + 128] = __bfloat162float(h[node * 256 + t + 128]);
    __syncthreads();
    float acc = Hb1[t];
    for (int k = 0; k < 256; k++) acc += row[k] * HW1[k * 128 + t];
    z1[t] = acc > 0.f ? acc : expm1f(acc);
    __syncthreads();
    acc = Hb2[t];
    for (int k = 0; k < 128; k++) acc += z1[k] * HW2[k * 128 + t];
    z2[t] = acc > 0.f ? acc : expm1f(acc);
    __syncthreads();
    if (t < 2) {
        acc = Hb3[t];
        for (int k = 0; k < 128; k++) acc += z2[k] * HW3[k * 2 + t];
        out[g * 2 + t] = acc;
    }
}

// ---------------- launch ----------------

extern "C" void kernel_launch(void* const* d_in, const int* in_sizes, int n_in,
                              void* d_out, int out_size, void* d_ws, size_t ws_size,
                              hipStream_t stream) {
    const int* x          = (const int*)d_in[0];
    const int* edge_index = (const int*)d_in[1];
    const int* edge_attr  = (const int*)d_in[2];
    const float* node_emb = (const float*)d_in[4];
    const float* ee1 = (const float*)d_in[5];
    const float* ee2 = (const float*)d_in[6];
    const float* ee3 = (const float*)d_in[7];
    const float* W1  = (const float*)d_in[8];
    const float* b1  = (const float*)d_in[9];
    const float* W2  = (const float*)d_in[10];
    const float* b2  = (const float*)d_in[11];
    const float* bng = (const float*)d_in[12];
    const float* bnb = (const float*)d_in[13];
    const float* HW1 = (const float*)d_in[14];
    const float* Hb1 = (const float*)d_in[15];
    const float* HW2 = (const float*)d_in[16];
    const float* Hb2 = (const float*)d_in[17];
    const float* HW3 = (const float*)d_in[18];
    const float* Hb3 = (const float*)d_in[19];
    float* out = (float*)d_out;

    char* ws = (char*)d_ws;
    size_t off = 0;
    auto alloc = [&](size_t bytes) -> char* {
        off = (off + 255) & ~(size_t)255;
        char* p = ws + off;
        off += bytes;
        return p;
    };
    int* deg       = (int*)alloc((size_t)NN * 4);
    int* cursor    = (int*)alloc((size_t)NN * 4);
    int* row_start = (int*)alloc((size_t)(NN + 1) * 4);
    int* eid       = (int*)alloc((size_t)ET * 4);
    int* combo     = (int*)alloc((size_t)ET * 4);
    float* ecomb   = (float*)alloc((size_t)LL * 300 * 256 * 4);
    __hip_bfloat16* W1t = (__hip_bfloat16*)alloc((size_t)LL * 512 * 256 * 2);
    __hip_bfloat16* W2t = (__hip_bfloat16*)alloc((size_t)LL * 256 * 512 * 2);
    __hip_bfloat16* h    = (__hip_bfloat16*)alloc((size_t)NN * 256 * 2);
    __hip_bfloat16* aggrB = (__hip_bfloat16*)alloc((size_t)NN * 256 * 2);
    __hip_bfloat16* act  = (__hip_bfloat16*)alloc((size_t)NN * 512 * 2);
    float* h2     = (float*)alloc((size_t)NN * 256 * 4);
    float* bnpart = (float*)alloc((size_t)320 * 256 * 2 * 4);
    float* bnstat = (float*)alloc((size_t)512 * 4);

    hipMemsetAsync(deg, 0, (size_t)NN * 4, stream);
    k_deg<<<(ET + 255) / 256, 256, 0, stream>>>(edge_index, deg);
    k_scan<<<1, 1024, 0, stream>>>(deg, row_start, cursor, NN);
    k_fill<<<(ET + 255) / 256, 256, 0, stream>>>(edge_index, edge_attr, cursor, eid, combo);
    k_ecomb<<<LL * 300, 256, 0, stream>>>(ee1, ee2, ee3, ecomb);
    k_w1t<<<(LL * 512 * 256 + 255) / 256, 256, 0, stream>>>(W1, W1t);
    k_w2t<<<(LL * 256 * 512 + 255) / 256, 256, 0, stream>>>(W2, W2t);
    k_nodeemb<<<NN, 256, 0, stream>>>(x, node_emb, h);

    for (int l = 0; l < LL; l++) {
        k_aggr<<<NN, 256, 0, stream>>>(h, ecomb + (size_t)l * 300 * 256, row_start,
                                       eid, combo, edge_index, aggrB);
        k_gemm<256, true, true><<<dim3(NN / 128, 8), 256, 0, stream>>>(
            aggrB, W1t + (size_t)l * 512 * 256, b1 + l * 512, act, 512);
        k_gemm<512, false, false><<<dim3(NN / 128, 4), 256, 0, stream>>>(
            act, W2t + (size_t)l * 256 * 512, b2 + l * 256, h2, 256);
        k_bn1<<<320, 256, 0, stream>>>(h2, bnpart, 250);
        k_bn2<<<1, 256, 0, stream>>>(bnpart, bng + l * 256, bnb + l * 256, bnstat, 320);
        k_bnapply<<<NN, 256, 0, stream>>>(h2, bnstat, h, (l < LL - 1) ? 1 : 0);
    }

    k_head<<<BB, 128, 0, stream>>>(h, HW1, Hb1, HW2, Hb2, HW3, Hb3, out);
}

// Round 3
// 2104.415 us; speedup vs baseline: 1.5594x; 1.5594x over previous
//
#include <hip/hip_runtime.h>
#include <hip/hip_bf16.h>

#define NN 80000
#define EE 320000
#define ET 400000   // EE + NN self loops
#define BB 3200
#define LL 5

typedef __attribute__((ext_vector_type(8))) short bf16x8;
typedef __attribute__((ext_vector_type(4))) float f32x4;

__device__ __forceinline__ float bf2f(unsigned short u) {
    unsigned int v = ((unsigned int)u) << 16;
    return __builtin_bit_cast(float, v);
}
__device__ __forceinline__ unsigned short f2bf(float f) {
    return __builtin_bit_cast(unsigned short, __float2bfloat16(f));
}

// ---------------- preprocessing ----------------

__global__ void k_deg(const int* ei, int* deg) {
    int e = blockIdx.x * 256 + threadIdx.x;
    if (e >= ET) return;
    int d = (e < EE) ? ei[EE + e] : (e - EE);
    atomicAdd(&deg[d], 1);
}

__global__ __launch_bounds__(1024) void k_scan(const int* deg, int* row_start, int* cursor, int n) {
    __shared__ int part[1024];
    int t = threadIdx.x;
    int per = (n + 1023) / 1024;
    int b0 = t * per, b1 = b0 + per;
    if (b1 > n) b1 = n;
    int s = 0;
    for (int i = b0; i < b1; i++) s += deg[i];
    part[t] = s;
    __syncthreads();
    for (int off = 1; off < 1024; off <<= 1) {
        int x = (t >= off) ? part[t - off] : 0;
        __syncthreads();
        part[t] += x;
        __syncthreads();
    }
    int run = part[t] - s;   // exclusive prefix of this segment
    for (int i = b0; i < b1; i++) {
        row_start[i] = run; cursor[i] = run; run += deg[i];
    }
    if (t == 1023) row_start[n] = run;
}

__global__ void k_fill(const int* ei, const int* ea, int* cursor, int* eid, int* combo) {
    int e = blockIdx.x * 256 + threadIdx.x;
    if (e >= ET) return;
    int d = (e < EE) ? ei[EE + e] : (e - EE);
    int p = atomicAdd(&cursor[d], 1);
    eid[p] = e;
    int c;
    if (e < EE) c = ea[e * 3 + 0] * 12 + ea[e * 3 + 1] * 2 + ea[e * 3 + 2];
    else        c = 22 * 12;   // self loop attr [22,0,0]
    combo[e] = c;
}

// deterministic edge order within each node bucket (atomics fill in random order)
__global__ void k_sortbkt(const int* row_start, int* eid) {
    int v = blockIdx.x * 256 + threadIdx.x;
    if (v >= NN) return;
    int s0 = row_start[v], s1 = row_start[v + 1];
    for (int i = s0 + 1; i < s1; i++) {
        int key = eid[i];
        int j = i - 1;
        while (j >= s0 && eid[j] > key) { eid[j + 1] = eid[j]; j--; }
        eid[j + 1] = key;
    }
}

__global__ void k_ecomb(const float* e1, const float* e2, const float* e3, float* ec) {
    int l = blockIdx.x / 300, c = blockIdx.x % 300, d = threadIdx.x;
    int a0 = c / 12, a1 = (c / 2) % 6, a2 = c & 1;
    ec[(size_t)(l * 300 + c) * 256 + d] =
        e1[(size_t)(l * 25 + a0) * 256 + d] +
        e2[(size_t)(l * 6 + a1) * 256 + d] +
        e3[(size_t)(l * 2 + a2) * 256 + d];
}

// W1: [L][256][512] -> W1t: [L][512][256] bf16
__global__ void k_w1t(const float* W, __hip_bfloat16* Wt) {
    int i = blockIdx.x * 256 + threadIdx.x;
    if (i >= LL * 512 * 256) return;
    int l = i / (512 * 256); int r = i % (512 * 256); int n = r / 256; int k = r % 256;
    Wt[i] = __float2bfloat16(W[(size_t)(l * 256 + k) * 512 + n]);
}
// W2: [L][512][256] -> W2t: [L][256][512] bf16
__global__ void k_w2t(const float* W, __hip_bfloat16* Wt) {
    int i = blockIdx.x * 256 + threadIdx.x;
    if (i >= LL * 256 * 512) return;
    int l = i / (256 * 512); int r = i % (256 * 512); int n = r / 512; int k = r % 512;
    Wt[i] = __float2bfloat16(W[(size_t)(l * 512 + k) * 256 + n]);
}

__global__ void k_nodeemb(const int* x, const float* emb, __hip_bfloat16* h) {
    const int offs[9] = {0, 121, 129, 141, 156, 166, 175, 182, 185};
    int i = blockIdx.x; int d = threadIdx.x;
    float acc = 0.f;
#pragma unroll
    for (int c = 0; c < 9; c++) {
        int idx = x[i * 9 + c] + offs[c];
        acc += emb[(size_t)idx * 256 + d];
    }
    h[(size_t)i * 256 + d] = __float2bfloat16(acc);
}

// ---------------- per-layer ----------------

// one wave per node, lane handles 4 columns (8B bf16 loads)
__global__ __launch_bounds__(256) void k_aggr(const __hip_bfloat16* h, const float* ecomb_l,
        const int* row_start, const int* eid, const int* combo, const int* ei_src,
        __hip_bfloat16* aggrB) {
    int v = blockIdx.x * 4 + (threadIdx.x >> 6);
    if (v >= NN) return;
    int lane = threadIdx.x & 63;
    int s0 = row_start[v], s1 = row_start[v + 1];
    const unsigned short* hp = (const unsigned short*)h;
    float a0 = 0.f, a1 = 0.f, a2 = 0.f, a3 = 0.f;
    for (int p = s0; p < s1; p++) {
        int e = eid[p];
        int s = (e < EE) ? ei_src[e] : (e - EE);
        int c = combo[e];
        ushort4 hv = *(const ushort4*)(hp + (size_t)s * 256 + lane * 4);
        f32x4 ev = *(const f32x4*)(ecomb_l + (size_t)c * 256 + lane * 4);
        a0 += bf2f(hv.x) + ev.x;
        a1 += bf2f(hv.y) + ev.y;
        a2 += bf2f(hv.z) + ev.z;
        a3 += bf2f(hv.w) + ev.w;
    }
    ushort4 o;
    o.x = f2bf(a0); o.y = f2bf(a1);
    o.z = f2bf(a2); o.w = f2bf(a3);
    *(ushort4*)((unsigned short*)aggrB + (size_t)v * 256 + lane * 4) = o;
}

// C[M,Nn] = act( A[M,K](bf16) * Wt[Nn,K]^T (bf16) + bias )
// m97 structure: 128x128 tile, BK=32, 4 waves (2x2), global_load_lds w=16, linear LDS
template<int K, bool RELU, bool OUTBF>
__global__ __launch_bounds__(256) void k_gemm(const __hip_bfloat16* A, const __hip_bfloat16* Wt,
                                              const float* bias, void* out, int Nn) {
    __shared__ short lA[128 * 32];
    __shared__ short lB[128 * 32];
    int tid = threadIdx.x;
    int wave = tid >> 6, lane = tid & 63;
    int mBase = blockIdx.x * 128;
    int nBase = blockIdx.y * 128;
    int wr = (wave >> 1) * 64;   // wave row offset in tile
    int wc = (wave & 1) * 64;    // wave col offset in tile
    int lr = lane & 15, lk = lane >> 4;
    const short* Ap = (const short*)A + (size_t)mBase * K;
    const short* Bp = (const short*)Wt + (size_t)nBase * K;
    // staging geometry: chunk = 1KB = 16 rows x 32 cols; lane l -> row chunk*16 + l/4, col (l&3)*8
    int srow = (lane >> 2);
    int scol = (lane & 3) * 8;
    f32x4 acc[4][4] = {};

    for (int k0 = 0; k0 < K; k0 += 32) {
#pragma unroll
        for (int i = 0; i < 2; i++) {
            int chunk = wave * 2 + i;
            int row = chunk * 16 + srow;
            __builtin_amdgcn_global_load_lds(
                (const __attribute__((address_space(1))) unsigned int*)(Ap + (size_t)row * K + k0 + scol),
                (__attribute__((address_space(3))) unsigned int*)(&lA[chunk * 512]), 16, 0, 0);
            __builtin_amdgcn_global_load_lds(
                (const __attribute__((address_space(1))) unsigned int*)(Bp + (size_t)row * K + k0 + scol),
                (__attribute__((address_space(3))) unsigned int*)(&lB[chunk * 512]), 16, 0, 0);
        }
        __syncthreads();   // drains vmcnt before barrier -> staging complete
        bf16x8 a[4], b[4];
#pragma unroll
        for (int m = 0; m < 4; m++)
            a[m] = *(const bf16x8*)(&lA[(wr + m * 16 + lr) * 32 + lk * 8]);
#pragma unroll
        for (int n = 0; n < 4; n++)
            b[n] = *(const bf16x8*)(&lB[(wc + n * 16 + lr) * 32 + lk * 8]);
#pragma unroll
        for (int m = 0; m < 4; m++)
#pragma unroll
            for (int n = 0; n < 4; n++)
                acc[m][n] = __builtin_amdgcn_mfma_f32_16x16x32_bf16(a[m], b[n], acc[m][n], 0, 0, 0);
        __syncthreads();   // all waves done reading before next overwrite
    }

#pragma unroll
    for (int m = 0; m < 4; m++)
#pragma unroll
        for (int n = 0; n < 4; n++) {
            int cdx = nBase + wc + n * 16 + lr;
            float bi = bias[cdx];
#pragma unroll
            for (int j = 0; j < 4; j++) {
                int r = mBase + wr + m * 16 + lk * 4 + j;
                float v = acc[m][n][j] + bi;
                if (RELU) v = fmaxf(v, 0.f);
                if (OUTBF) ((__hip_bfloat16*)out)[(size_t)r * Nn + cdx] = __float2bfloat16(v);
                else       ((float*)out)[(size_t)r * Nn + cdx] = v;
            }
        }
}

__global__ void k_bn1(const float* h2, float* part, int rowsPerBlk) {
    int d = threadIdx.x; int b = blockIdx.x;
    int r0 = b * rowsPerBlk, r1 = r0 + rowsPerBlk;
    if (r1 > NN) r1 = NN;
    float s = 0.f, s2 = 0.f;
    for (int r = r0; r < r1; r++) {
        float v = h2[(size_t)r * 256 + d];
        s += v; s2 += v * v;
    }
    part[(size_t)(b * 256 + d) * 2]     = s;
    part[(size_t)(b * 256 + d) * 2 + 1] = s2;
}

__global__ void k_bn2(const float* part, const float* g, const float* bta, float* stat, int nb) {
    int d = threadIdx.x;
    float s = 0.f, s2 = 0.f;
    for (int b = 0; b < nb; b++) {
        s  += part[(size_t)(b * 256 + d) * 2];
        s2 += part[(size_t)(b * 256 + d) * 2 + 1];
    }
    float mean = s / NN;
    float var = s2 / NN - mean * mean;
    float sc = rsqrtf(var + 1e-5f) * g[d];
    stat[d] = sc;
    stat[256 + d] = bta[d] - mean * sc;
}

__global__ void k_bnapply(const float* h2, const float* stat, __hip_bfloat16* h, int relu) {
    int i = blockIdx.x * 256 + threadIdx.x;   // over NN*256
    int d = i & 255;
    float v = h2[i] * stat[d] + stat[256 + d];
    if (relu) v = fmaxf(v, 0.f);
    h[i] = __float2bfloat16(v);
}

// ---------------- head ----------------

__global__ __launch_bounds__(128) void k_head(const __hip_bfloat16* h,
        const float* HW1, const float* Hb1, const float* HW2, const float* Hb2,
        const float* HW3, const float* Hb3, float* out) {
    __shared__ float row[256], z1[128], z2[128];
    int g = blockIdx.x; int t = threadIdx.x;
    size_t node = (size_t)g * 25 + 24;
    row[t]       = __bfloat162float(h[node * 256 + t]);
    row[t + 128] = __bfloat162float(h[node * 256 + t + 128]);
    __syncthreads();
    float acc = Hb1[t];
    for (int k = 0; k < 256; k++) acc += row[k] * HW1[k * 128 + t];
    z1[t] = acc > 0.f ? acc : expm1f(acc);
    __syncthreads();
    acc = Hb2[t];
    for (int k = 0; k < 128; k++) acc += z1[k] * HW2[k * 128 + t];
    z2[t] = acc > 0.f ? acc : expm1f(acc);
    __syncthreads();
    if (t < 2) {
        acc = Hb3[t];
        for (int k = 0; k < 128; k++) acc += z2[k] * HW3[k * 2 + t];
        out[g * 2 + t] = acc;
    }
}

// ---------------- launch ----------------

extern "C" void kernel_launch(void* const* d_in, const int* in_sizes, int n_in,
                              void* d_out, int out_size, void* d_ws, size_t ws_size,
                              hipStream_t stream) {
    const int* x          = (const int*)d_in[0];
    const int* edge_index = (const int*)d_in[1];
    const int* edge_attr  = (const int*)d_in[2];
    const float* node_emb = (const float*)d_in[4];
    const float* ee1 = (const float*)d_in[5];
    const float* ee2 = (const float*)d_in[6];
    const float* ee3 = (const float*)d_in[7];
    const float* W1  = (const float*)d_in[8];
    const float* b1  = (const float*)d_in[9];
    const float* W2  = (const float*)d_in[10];
    const float* b2  = (const float*)d_in[11];
    const float* bng = (const float*)d_in[12];
    const float* bnb = (const float*)d_in[13];
    const float* HW1 = (const float*)d_in[14];
    const float* Hb1 = (const float*)d_in[15];
    const float* HW2 = (const float*)d_in[16];
    const float* Hb2 = (const float*)d_in[17];
    const float* HW3 = (const float*)d_in[18];
    const float* Hb3 = (const float*)d_in[19];
    float* out = (float*)d_out;

    char* ws = (char*)d_ws;
    size_t off = 0;
    auto alloc = [&](size_t bytes) -> char* {
        off = (off + 255) & ~(size_t)255;
        char* p = ws + off;
        off += bytes;
        return p;
    };
    int* deg       = (int*)alloc((size_t)NN * 4);
    int* cursor    = (int*)alloc((size_t)NN * 4);
    int* row_start = (int*)alloc((size_t)(NN + 1) * 4);
    int* eid       = (int*)alloc((size_t)ET * 4);
    int* combo     = (int*)alloc((size_t)ET * 4);
    float* ecomb   = (float*)alloc((size_t)LL * 300 * 256 * 4);
    __hip_bfloat16* W1t = (__hip_bfloat16*)alloc((size_t)LL * 512 * 256 * 2);
    __hip_bfloat16* W2t = (__hip_bfloat16*)alloc((size_t)LL * 256 * 512 * 2);
    __hip_bfloat16* h    = (__hip_bfloat16*)alloc((size_t)NN * 256 * 2);
    __hip_bfloat16* aggrB = (__hip_bfloat16*)alloc((size_t)NN * 256 * 2);
    __hip_bfloat16* act  = (__hip_bfloat16*)alloc((size_t)NN * 512 * 2);
    float* h2     = (float*)alloc((size_t)NN * 256 * 4);
    float* bnpart = (float*)alloc((size_t)320 * 256 * 2 * 4);
    float* bnstat = (float*)alloc((size_t)512 * 4);

    hipMemsetAsync(deg, 0, (size_t)NN * 4, stream);
    k_deg<<<(ET + 255) / 256, 256, 0, stream>>>(edge_index, deg);
    k_scan<<<1, 1024, 0, stream>>>(deg, row_start, cursor, NN);
    k_fill<<<(ET + 255) / 256, 256, 0, stream>>>(edge_index, edge_attr, cursor, eid, combo);
    k_sortbkt<<<(NN + 255) / 256, 256, 0, stream>>>(row_start, eid);
    k_ecomb<<<LL * 300, 256, 0, stream>>>(ee1, ee2, ee3, ecomb);
    k_w1t<<<(LL * 512 * 256 + 255) / 256, 256, 0, stream>>>(W1, W1t);
    k_w2t<<<(LL * 256 * 512 + 255) / 256, 256, 0, stream>>>(W2, W2t);
    k_nodeemb<<<NN, 256, 0, stream>>>(x, node_emb, h);

    for (int l = 0; l < LL; l++) {
        k_aggr<<<(NN + 3) / 4, 256, 0, stream>>>(h, ecomb + (size_t)l * 300 * 256, row_start,
                                                 eid, combo, edge_index, aggrB);
        k_gemm<256, true, true><<<dim3(625, 4), 256, 0, stream>>>(
            aggrB, W1t + (size_t)l * 512 * 256, b1 + l * 512, act, 512);
        k_gemm<512, false, false><<<dim3(625, 2), 256, 0, stream>>>(
            act, W2t + (size_t)l * 256 * 512, b2 + l * 256, h2, 256);
        k_bn1<<<320, 256, 0, stream>>>(h2, bnpart, 250);
        k_bn2<<<1, 256, 0, stream>>>(bnpart, bng + l * 256, bnb + l * 256, bnstat, 320);
        k_bnapply<<<NN, 256, 0, stream>>>(h2, bnstat, h, (l < LL - 1) ? 1 : 0);
    }

    k_head<<<BB, 128, 0, stream>>>(h, HW1, Hb1, HW2, Hb2, HW3, Hb3, out);
}

// Round 5
// 1036.688 us; speedup vs baseline: 3.1655x; 2.0299x over previous
//
#include <hip/hip_runtime.h>
#include <hip/hip_bf16.h>

#define NN 80000
#define EE 320000
#define ET 400000   // EE + NN self loops
#define BB 3200
#define LL 5
#define NBLK 313    // ceil(NN/256)

typedef __attribute__((ext_vector_type(8))) short bf16x8;
typedef __attribute__((ext_vector_type(4))) float f32x4;

__device__ __forceinline__ float bf2f(unsigned short u) {
    unsigned int v = ((unsigned int)u) << 16;
    return __builtin_bit_cast(float, v);
}
__device__ __forceinline__ unsigned short f2bf(float f) {
    return __builtin_bit_cast(unsigned short, __float2bfloat16(f));
}

// ---------------- preprocessing ----------------

__global__ void k_deg(const int* ei, int* deg) {
    int e = blockIdx.x * 256 + threadIdx.x;
    if (e >= ET) return;
    int d = (e < EE) ? ei[EE + e] : (e - EE);
    atomicAdd(&deg[d], 1);
}

__global__ void k_scan1(const int* deg, int* blksum) {
    __shared__ int sh[256];
    int t = threadIdx.x, b = blockIdx.x;
    int i = b * 256 + t;
    int v = (i < NN) ? deg[i] : 0;
    sh[t] = v; __syncthreads();
    for (int off = 128; off > 0; off >>= 1) {
        if (t < off) sh[t] += sh[t + off];
        __syncthreads();
    }
    if (t == 0) blksum[b] = sh[0];
}

__global__ __launch_bounds__(512) void k_scan2(const int* blksum, int* blkoff) {
    __shared__ int sh[512];
    int t = threadIdx.x;
    int v = (t < NBLK) ? blksum[t] : 0;
    sh[t] = v; __syncthreads();
    for (int off = 1; off < 512; off <<= 1) {
        int x = (t >= off) ? sh[t - off] : 0;
        __syncthreads();
        sh[t] += x;
        __syncthreads();
    }
    if (t < NBLK) blkoff[t] = sh[t] - v;   // exclusive
}

__global__ void k_scan3(const int* deg, const int* blkoff, int* row_start, int* cursor) {
    __shared__ int sh[256];
    int t = threadIdx.x, b = blockIdx.x;
    int i = b * 256 + t;
    int v = (i < NN) ? deg[i] : 0;
    sh[t] = v; __syncthreads();
    for (int off = 1; off < 256; off <<= 1) {
        int x = (t >= off) ? sh[t - off] : 0;
        __syncthreads();
        sh[t] += x;
        __syncthreads();
    }
    int exc = sh[t] - v + blkoff[b];
    if (i < NN) { row_start[i] = exc; cursor[i] = exc; }
    if (i == NN - 1) row_start[NN] = exc + v;
}

__global__ void k_fill(const int* ei, const int* ea, int* cursor, int* eid, int* combo) {
    int e = blockIdx.x * 256 + threadIdx.x;
    if (e >= ET) return;
    int d = (e < EE) ? ei[EE + e] : (e - EE);
    int p = atomicAdd(&cursor[d], 1);
    eid[p] = e;
    int c;
    if (e < EE) c = ea[e * 3 + 0] * 12 + ea[e * 3 + 1] * 2 + ea[e * 3 + 2];
    else        c = 22 * 12;   // self loop attr [22,0,0]
    combo[e] = c;
}

// deterministic edge order within each node bucket (atomics fill in random order)
__global__ void k_sortbkt(const int* row_start, int* eid) {
    int v = blockIdx.x * 256 + threadIdx.x;
    if (v >= NN) return;
    int s0 = row_start[v], s1 = row_start[v + 1];
    for (int i = s0 + 1; i < s1; i++) {
        int key = eid[i];
        int j = i - 1;
        while (j >= s0 && eid[j] > key) { eid[j + 1] = eid[j]; j--; }
        eid[j + 1] = key;
    }
}

// flatten eid indirection: csrc[p]=source node, ccomb[p]=edge combo, in CSR order
__global__ void k_remap(const int* eid, const int* combo, const int* ei_src,
                        int* csrc, int* ccomb) {
    int p = blockIdx.x * 256 + threadIdx.x;
    if (p >= ET) return;
    int e = eid[p];
    csrc[p]  = (e < EE) ? ei_src[e] : (e - EE);
    ccomb[p] = combo[e];
}

__global__ void k_ecomb(const float* e1, const float* e2, const float* e3, float* ec) {
    int l = blockIdx.x / 300, c = blockIdx.x % 300, d = threadIdx.x;
    int a0 = c / 12, a1 = (c / 2) % 6, a2 = c & 1;
    ec[(size_t)(l * 300 + c) * 256 + d] =
        e1[(size_t)(l * 25 + a0) * 256 + d] +
        e2[(size_t)(l * 6 + a1) * 256 + d] +
        e3[(size_t)(l * 2 + a2) * 256 + d];
}

// W1: [L][256][512] -> W1t: [L][512][256] bf16
__global__ void k_w1t(const float* W, __hip_bfloat16* Wt) {
    int i = blockIdx.x * 256 + threadIdx.x;
    if (i >= LL * 512 * 256) return;
    int l = i / (512 * 256); int r = i % (512 * 256); int n = r / 256; int k = r % 256;
    Wt[i] = __float2bfloat16(W[(size_t)(l * 256 + k) * 512 + n]);
}
// W2: [L][512][256] -> W2t: [L][256][512] bf16
__global__ void k_w2t(const float* W, __hip_bfloat16* Wt) {
    int i = blockIdx.x * 256 + threadIdx.x;
    if (i >= LL * 256 * 512) return;
    int l = i / (256 * 512); int r = i % (256 * 512); int n = r / 512; int k = r % 512;
    Wt[i] = __float2bfloat16(W[(size_t)(l * 512 + k) * 256 + n]);
}

__global__ void k_nodeemb(const int* x, const float* emb, __hip_bfloat16* h) {
    const int offs[9] = {0, 121, 129, 141, 156, 166, 175, 182, 185};
    int i = blockIdx.x; int d = threadIdx.x;
    float acc = 0.f;
#pragma unroll
    for (int c = 0; c < 9; c++) {
        int idx = x[i * 9 + c] + offs[c];
        acc += emb[(size_t)idx * 256 + d];
    }
    h[(size_t)i * 256 + d] = __float2bfloat16(acc);
}

// ---------------- per-layer ----------------

// one wave per node, lane handles 4 columns (8B bf16 loads)
__global__ __launch_bounds__(256) void k_aggr(const __hip_bfloat16* h, const float* ecomb_l,
        const int* row_start, const int* csrc, const int* ccomb,
        __hip_bfloat16* aggrB) {
    int v = blockIdx.x * 4 + (threadIdx.x >> 6);
    if (v >= NN) return;
    int lane = threadIdx.x & 63;
    int s0 = row_start[v], s1 = row_start[v + 1];
    const unsigned short* hp = (const unsigned short*)h;
    float a0 = 0.f, a1 = 0.f, a2 = 0.f, a3 = 0.f;
    for (int p = s0; p < s1; p++) {
        int s = csrc[p];
        int c = ccomb[p];
        ushort4 hv = *(const ushort4*)(hp + (size_t)s * 256 + lane * 4);
        f32x4 ev = *(const f32x4*)(ecomb_l + (size_t)c * 256 + lane * 4);
        a0 += bf2f(hv.x) + ev.x;
        a1 += bf2f(hv.y) + ev.y;
        a2 += bf2f(hv.z) + ev.z;
        a3 += bf2f(hv.w) + ev.w;
    }
    ushort4 o;
    o.x = f2bf(a0); o.y = f2bf(a1);
    o.z = f2bf(a2); o.w = f2bf(a3);
    *(ushort4*)((unsigned short*)aggrB + (size_t)v * 256 + lane * 4) = o;
}

// C[M,Nn] = act( A[M,K](bf16) * Wt[Nn,K]^T (bf16) + bias )
// m97 structure: 128x128 tile, BK=32, 4 waves (2x2), global_load_lds w=16, linear LDS
// STATS: also emit per-block per-column {sum, sumsq} partials (deterministic BN stats)
template<int K, bool RELU, bool OUTBF, bool STATS>
__global__ __launch_bounds__(256) void k_gemm(const __hip_bfloat16* A, const __hip_bfloat16* Wt,
                                              const float* bias, void* out, int Nn,
                                              float* psum, float* psq) {
    __shared__ short lA[128 * 32];
    __shared__ short lB[128 * 32];
    __shared__ float redS[4][64], redQ[4][64];
    int tid = threadIdx.x;
    int wave = tid >> 6, lane = tid & 63;
    int mBase = blockIdx.x * 128;
    int nBase = blockIdx.y * 128;
    int wr = (wave >> 1) * 64;   // wave row offset in tile
    int wc = (wave & 1) * 64;    // wave col offset in tile
    int lr = lane & 15, lk = lane >> 4;
    const short* Ap = (const short*)A + (size_t)mBase * K;
    const short* Bp = (const short*)Wt + (size_t)nBase * K;
    // staging geometry: chunk = 1KB = 16 rows x 32 cols; lane l -> row chunk*16 + l/4, col (l&3)*8
    int srow = (lane >> 2);
    int scol = (lane & 3) * 8;
    f32x4 acc[4][4] = {};

    for (int k0 = 0; k0 < K; k0 += 32) {
#pragma unroll
        for (int i = 0; i < 2; i++) {
            int chunk = wave * 2 + i;
            int row = chunk * 16 + srow;
            __builtin_amdgcn_global_load_lds(
                (const __attribute__((address_space(1))) unsigned int*)(Ap + (size_t)row * K + k0 + scol),
                (__attribute__((address_space(3))) unsigned int*)(&lA[chunk * 512]), 16, 0, 0);
            __builtin_amdgcn_global_load_lds(
                (const __attribute__((address_space(1))) unsigned int*)(Bp + (size_t)row * K + k0 + scol),
                (__attribute__((address_space(3))) unsigned int*)(&lB[chunk * 512]), 16, 0, 0);
        }
        __syncthreads();   // drains vmcnt before barrier -> staging complete
        bf16x8 a[4], b[4];
#pragma unroll
        for (int m = 0; m < 4; m++)
            a[m] = *(const bf16x8*)(&lA[(wr + m * 16 + lr) * 32 + lk * 8]);
#pragma unroll
        for (int n = 0; n < 4; n++)
            b[n] = *(const bf16x8*)(&lB[(wc + n * 16 + lr) * 32 + lk * 8]);
#pragma unroll
        for (int m = 0; m < 4; m++)
#pragma unroll
            for (int n = 0; n < 4; n++)
                acc[m][n] = __builtin_amdgcn_mfma_f32_16x16x32_bf16(a[m], b[n], acc[m][n], 0, 0, 0);
        __syncthreads();   // all waves done reading before next overwrite
    }

    float colS[4] = {0.f, 0.f, 0.f, 0.f}, colQ[4] = {0.f, 0.f, 0.f, 0.f};
#pragma unroll
    for (int m = 0; m < 4; m++)
#pragma unroll
        for (int n = 0; n < 4; n++) {
            int cdx = nBase + wc + n * 16 + lr;
            float bi = bias[cdx];
#pragma unroll
            for (int j = 0; j < 4; j++) {
                int r = mBase + wr + m * 16 + lk * 4 + j;
                float v = acc[m][n][j] + bi;
                if (RELU) v = fmaxf(v, 0.f);
                if (OUTBF) ((__hip_bfloat16*)out)[(size_t)r * Nn + cdx] = __float2bfloat16(v);
                else       ((float*)out)[(size_t)r * Nn + cdx] = v;
                if (STATS) { colS[n] += v; colQ[n] += v * v; }
            }
        }

    if (STATS) {
#pragma unroll
        for (int n = 0; n < 4; n++) {
            for (int off = 16; off < 64; off <<= 1) {
                colS[n] += __shfl_xor(colS[n], off);
                colQ[n] += __shfl_xor(colQ[n], off);
            }
        }
        if (lk == 0) {
#pragma unroll
            for (int n = 0; n < 4; n++) {
                redS[wave][n * 16 + lr] = colS[n];
                redQ[wave][n * 16 + lr] = colQ[n];
            }
        }
        __syncthreads();
        if (tid < 128) {
            int c = tid;
            int w0 = (c < 64) ? 0 : 1;
            int cc = c & 63;
            float S = redS[w0][cc] + redS[w0 + 2][cc];
            float Q = redQ[w0][cc] + redQ[w0 + 2][cc];
            psum[(size_t)(nBase + c) * 625 + blockIdx.x] = S;
            psq [(size_t)(nBase + c) * 625 + blockIdx.x] = Q;
        }
    }
}

// one block per column: reduce 625 row-block partials -> scale/shift
__global__ __launch_bounds__(256) void k_bn2(const float* psum, const float* psq,
                                             const float* g, const float* bta, float* stat) {
    __shared__ float s1[256], s2[256];
    int d = blockIdx.x; int t = threadIdx.x;
    float a = 0.f, b = 0.f;
    for (int rb = t; rb < 625; rb += 256) {
        a += psum[(size_t)d * 625 + rb];
        b += psq [(size_t)d * 625 + rb];
    }
    s1[t] = a; s2[t] = b; __syncthreads();
    for (int off = 128; off > 0; off >>= 1) {
        if (t < off) { s1[t] += s1[t + off]; s2[t] += s2[t + off]; }
        __syncthreads();
    }
    if (t == 0) {
        float mean = s1[0] / NN;
        float var = s2[0] / NN - mean * mean;
        float sc = rsqrtf(var + 1e-5f) * g[d];
        stat[d] = sc;
        stat[256 + d] = bta[d] - mean * sc;
    }
}

// vectorized: 4 f32 in, 4 bf16 out per thread; grid covers NN*256/4 threads
__global__ void k_bnapply(const float* h2, const float* stat, __hip_bfloat16* h, int relu) {
    int i = (blockIdx.x * 256 + threadIdx.x) * 4;   // over NN*256
    int d = i & 255;
    f32x4 v = *(const f32x4*)(h2 + i);
    f32x4 sc = *(const f32x4*)(stat + d);
    f32x4 sh = *(const f32x4*)(stat + 256 + d);
    float r0 = v.x * sc.x + sh.x;
    float r1 = v.y * sc.y + sh.y;
    float r2 = v.z * sc.z + sh.z;
    float r3 = v.w * sc.w + sh.w;
    if (relu) {
        r0 = fmaxf(r0, 0.f); r1 = fmaxf(r1, 0.f);
        r2 = fmaxf(r2, 0.f); r3 = fmaxf(r3, 0.f);
    }
    ushort4 o;
    o.x = f2bf(r0); o.y = f2bf(r1); o.z = f2bf(r2); o.w = f2bf(r3);
    *(ushort4*)((unsigned short*)h + i) = o;
}

// ---------------- head ----------------

__global__ __launch_bounds__(128) void k_head(const __hip_bfloat16* h,
        const float* HW1, const float* Hb1, const float* HW2, const float* Hb2,
        const float* HW3, const float* Hb3, float* out) {
    __shared__ float row[256], z1[128], z2[128];
    int g = blockIdx.x; int t = threadIdx.x;
    size_t node = (size_t)g * 25 + 24;
    row[t]       = __bfloat162float(h[node * 256 + t]);
    row[t + 128] = __bfloat162float(h[node * 256 + t + 128]);
    __syncthreads();
    float acc = Hb1[t];
    for (int k = 0; k < 256; k++) acc += row[k] * HW1[k * 128 + t];
    z1[t] = acc > 0.f ? acc : expm1f(acc);
    __syncthreads();
    acc = Hb2[t];
    for (int k = 0; k < 128; k++) acc += z1[k] * HW2[k * 128 + t];
    z2[t] = acc > 0.f ? acc : expm1f(acc);
    __syncthreads();
    if (t < 2) {
        acc = Hb3[t];
        for (int k = 0; k < 128; k++) acc += z2[k] * HW3[k * 2 + t];
        out[g * 2 + t] = acc;
    }
}

// ---------------- launch ----------------

extern "C" void kernel_launch(void* const* d_in, const int* in_sizes, int n_in,
                              void* d_out, int out_size, void* d_ws, size_t ws_size,
                              hipStream_t stream) {
    const int* x          = (const int*)d_in[0];
    const int* edge_index = (const int*)d_in[1];
    const int* edge_attr  = (const int*)d_in[2];
    const float* node_emb = (const float*)d_in[4];
    const float* ee1 = (const float*)d_in[5];
    const float* ee2 = (const float*)d_in[6];
    const float* ee3 = (const float*)d_in[7];
    const float* W1  = (const float*)d_in[8];
    const float* b1  = (const float*)d_in[9];
    const float* W2  = (const float*)d_in[10];
    const float* b2  = (const float*)d_in[11];
    const float* bng = (const float*)d_in[12];
    const float* bnb = (const float*)d_in[13];
    const float* HW1 = (const float*)d_in[14];
    const float* Hb1 = (const float*)d_in[15];
    const float* HW2 = (const float*)d_in[16];
    const float* Hb2 = (const float*)d_in[17];
    const float* HW3 = (const float*)d_in[18];
    const float* Hb3 = (const float*)d_in[19];
    float* out = (float*)d_out;

    char* ws = (char*)d_ws;
    size_t off = 0;
    auto alloc = [&](size_t bytes) -> char* {
        off = (off + 255) & ~(size_t)255;
        char* p = ws + off;
        off += bytes;
        return p;
    };
    int* deg       = (int*)alloc((size_t)NN * 4);
    int* cursor    = (int*)alloc((size_t)NN * 4);
    int* row_start = (int*)alloc((size_t)(NN + 1) * 4);
    int* blksum    = (int*)alloc((size_t)(NBLK + 1) * 4);
    int* blkoff    = (int*)alloc((size_t)(NBLK + 1) * 4);
    int* eid       = (int*)alloc((size_t)ET * 4);
    int* combo     = (int*)alloc((size_t)ET * 4);
    int* csrc      = (int*)alloc((size_t)ET * 4);
    int* ccomb     = (int*)alloc((size_t)ET * 4);
    float* ecomb   = (float*)alloc((size_t)LL * 300 * 256 * 4);
    __hip_bfloat16* W1t = (__hip_bfloat16*)alloc((size_t)LL * 512 * 256 * 2);
    __hip_bfloat16* W2t = (__hip_bfloat16*)alloc((size_t)LL * 256 * 512 * 2);
    __hip_bfloat16* h    = (__hip_bfloat16*)alloc((size_t)NN * 256 * 2);
    __hip_bfloat16* aggrB = (__hip_bfloat16*)alloc((size_t)NN * 256 * 2);
    __hip_bfloat16* act  = (__hip_bfloat16*)alloc((size_t)NN * 512 * 2);
    float* h2     = (float*)alloc((size_t)NN * 256 * 4);
    float* psum   = (float*)alloc((size_t)256 * 625 * 4);
    float* psq    = (float*)alloc((size_t)256 * 625 * 4);
    float* bnstat = (float*)alloc((size_t)512 * 4);

    hipMemsetAsync(deg, 0, (size_t)NN * 4, stream);
    k_deg<<<(ET + 255) / 256, 256, 0, stream>>>(edge_index, deg);
    k_scan1<<<NBLK, 256, 0, stream>>>(deg, blksum);
    k_scan2<<<1, 512, 0, stream>>>(blksum, blkoff);
    k_scan3<<<NBLK, 256, 0, stream>>>(deg, blkoff, row_start, cursor);
    k_fill<<<(ET + 255) / 256, 256, 0, stream>>>(edge_index, edge_attr, cursor, eid, combo);
    k_sortbkt<<<(NN + 255) / 256, 256, 0, stream>>>(row_start, eid);
    k_remap<<<(ET + 255) / 256, 256, 0, stream>>>(eid, combo, edge_index, csrc, ccomb);
    k_ecomb<<<LL * 300, 256, 0, stream>>>(ee1, ee2, ee3, ecomb);
    k_w1t<<<(LL * 512 * 256 + 255) / 256, 256, 0, stream>>>(W1, W1t);
    k_w2t<<<(LL * 256 * 512 + 255) / 256, 256, 0, stream>>>(W2, W2t);
    k_nodeemb<<<NN, 256, 0, stream>>>(x, node_emb, h);

    for (int l = 0; l < LL; l++) {
        k_aggr<<<(NN + 3) / 4, 256, 0, stream>>>(h, ecomb + (size_t)l * 300 * 256, row_start,
                                                 csrc, ccomb, aggrB);
        k_gemm<256, true, true, false><<<dim3(625, 4), 256, 0, stream>>>(
            aggrB, W1t + (size_t)l * 512 * 256, b1 + l * 512, act, 512, nullptr, nullptr);
        k_gemm<512, false, false, true><<<dim3(625, 2), 256, 0, stream>>>(
            act, W2t + (size_t)l * 256 * 512, b2 + l * 256, h2, 256, psum, psq);
        k_bn2<<<256, 256, 0, stream>>>(psum, psq, bng + l * 256, bnb + l * 256, bnstat);
        k_bnapply<<<NN * 256 / (256 * 4), 256, 0, stream>>>(h2, bnstat, h, (l < LL - 1) ? 1 : 0);
    }

    k_head<<<BB, 128, 0, stream>>>(h, HW1, Hb1, HW2, Hb2, HW3, Hb3, out);
}

// Round 6
// 944.341 us; speedup vs baseline: 3.4750x; 1.0978x over previous
//
#include <hip/hip_runtime.h>
#include <hip/hip_bf16.h>

#define NN 80000
#define EE 320000
#define ET 400000   // EE + NN self loops
#define BB 3200
#define LL 5
#define NBLK 313    // ceil(NN/256)

typedef __attribute__((ext_vector_type(8))) short bf16x8;
typedef __attribute__((ext_vector_type(8))) unsigned short u16x8;
typedef __attribute__((ext_vector_type(4))) float f32x4;

__device__ __forceinline__ float bf2f(unsigned short u) {
    unsigned int v = ((unsigned int)u) << 16;
    return __builtin_bit_cast(float, v);
}
__device__ __forceinline__ unsigned short f2bf(float f) {
    return __builtin_bit_cast(unsigned short, __float2bfloat16(f));
}

// ---------------- preprocessing ----------------

__global__ void k_deg(const int* ei, int* deg) {
    int e = blockIdx.x * 256 + threadIdx.x;
    if (e >= ET) return;
    int d = (e < EE) ? ei[EE + e] : (e - EE);
    atomicAdd(&deg[d], 1);
}

__global__ void k_scan1(const int* deg, int* blksum) {
    __shared__ int sh[256];
    int t = threadIdx.x, b = blockIdx.x;
    int i = b * 256 + t;
    int v = (i < NN) ? deg[i] : 0;
    sh[t] = v; __syncthreads();
    for (int off = 128; off > 0; off >>= 1) {
        if (t < off) sh[t] += sh[t + off];
        __syncthreads();
    }
    if (t == 0) blksum[b] = sh[0];
}

__global__ __launch_bounds__(512) void k_scan2(const int* blksum, int* blkoff) {
    __shared__ int sh[512];
    int t = threadIdx.x;
    int v = (t < NBLK) ? blksum[t] : 0;
    sh[t] = v; __syncthreads();
    for (int off = 1; off < 512; off <<= 1) {
        int x = (t >= off) ? sh[t - off] : 0;
        __syncthreads();
        sh[t] += x;
        __syncthreads();
    }
    if (t < NBLK) blkoff[t] = sh[t] - v;   // exclusive
}

__global__ void k_scan3(const int* deg, const int* blkoff, int* row_start, int* cursor) {
    __shared__ int sh[256];
    int t = threadIdx.x, b = blockIdx.x;
    int i = b * 256 + t;
    int v = (i < NN) ? deg[i] : 0;
    sh[t] = v; __syncthreads();
    for (int off = 1; off < 256; off <<= 1) {
        int x = (t >= off) ? sh[t - off] : 0;
        __syncthreads();
        sh[t] += x;
        __syncthreads();
    }
    int exc = sh[t] - v + blkoff[b];
    if (i < NN) { row_start[i] = exc; cursor[i] = exc; }
    if (i == NN - 1) row_start[NN] = exc + v;
}

__global__ void k_fill(const int* ei, const int* ea, int* cursor, int* eid, int* combo) {
    int e = blockIdx.x * 256 + threadIdx.x;
    if (e >= ET) return;
    int d = (e < EE) ? ei[EE + e] : (e - EE);
    int p = atomicAdd(&cursor[d], 1);
    eid[p] = e;
    int c;
    if (e < EE) c = ea[e * 3 + 0] * 12 + ea[e * 3 + 1] * 2 + ea[e * 3 + 2];
    else        c = 22 * 12;   // self loop attr [22,0,0]
    combo[e] = c;
}

// deterministic edge order within each node bucket (atomics fill in random order)
__global__ void k_sortbkt(const int* row_start, int* eid) {
    int v = blockIdx.x * 256 + threadIdx.x;
    if (v >= NN) return;
    int s0 = row_start[v], s1 = row_start[v + 1];
    for (int i = s0 + 1; i < s1; i++) {
        int key = eid[i];
        int j = i - 1;
        while (j >= s0 && eid[j] > key) { eid[j + 1] = eid[j]; j--; }
        eid[j + 1] = key;
    }
}

// flatten eid indirection: csrc[p]=source node, ccomb[p]=edge combo, in CSR order
__global__ void k_remap(const int* eid, const int* combo, const int* ei_src,
                        int* csrc, int* ccomb) {
    int p = blockIdx.x * 256 + threadIdx.x;
    if (p >= ET) return;
    int e = eid[p];
    csrc[p]  = (e < EE) ? ei_src[e] : (e - EE);
    ccomb[p] = combo[e];
}

__global__ void k_ecomb(const float* e1, const float* e2, const float* e3, float* ec) {
    int l = blockIdx.x / 300, c = blockIdx.x % 300, d = threadIdx.x;
    int a0 = c / 12, a1 = (c / 2) % 6, a2 = c & 1;
    ec[(size_t)(l * 300 + c) * 256 + d] =
        e1[(size_t)(l * 25 + a0) * 256 + d] +
        e2[(size_t)(l * 6 + a1) * 256 + d] +
        e3[(size_t)(l * 2 + a2) * 256 + d];
}

// W1: [L][256][512] -> W1t: [L][512][256] bf16
__global__ void k_w1t(const float* W, __hip_bfloat16* Wt) {
    int i = blockIdx.x * 256 + threadIdx.x;
    if (i >= LL * 512 * 256) return;
    int l = i / (512 * 256); int r = i % (512 * 256); int n = r / 256; int k = r % 256;
    Wt[i] = __float2bfloat16(W[(size_t)(l * 256 + k) * 512 + n]);
}
// W2: [L][512][256] -> W2t: [L][256][512] bf16
__global__ void k_w2t(const float* W, __hip_bfloat16* Wt) {
    int i = blockIdx.x * 256 + threadIdx.x;
    if (i >= LL * 256 * 512) return;
    int l = i / (256 * 512); int r = i % (256 * 512); int n = r / 512; int k = r % 512;
    Wt[i] = __float2bfloat16(W[(size_t)(l * 512 + k) * 256 + n]);
}

__global__ void k_nodeemb(const int* x, const float* emb, __hip_bfloat16* h) {
    const int offs[9] = {0, 121, 129, 141, 156, 166, 175, 182, 185};
    int i = blockIdx.x; int d = threadIdx.x;
    float acc = 0.f;
#pragma unroll
    for (int c = 0; c < 9; c++) {
        int idx = x[i * 9 + c] + offs[c];
        acc += emb[(size_t)idx * 256 + d];
    }
    h[(size_t)i * 256 + d] = __float2bfloat16(acc);
}

// ---------------- per-layer ----------------

// 2 nodes per wave: lanes 0-31 -> node A, 32-63 -> node B; 8 cols (16B) per lane.
// Per-node accumulation order identical to before (p ascending) -> bit-identical.
__global__ __launch_bounds__(256) void k_aggr(const __hip_bfloat16* h, const float* ecomb_l,
        const int* row_start, const int* csrc, const int* ccomb,
        __hip_bfloat16* aggrB) {
    int wid = threadIdx.x >> 6;
    int lane = threadIdx.x & 63;
    int v = blockIdx.x * 8 + wid * 2 + (lane >> 5);   // NN=80000 = 10000*8, always valid
    int sl = lane & 31;
    int s0 = row_start[v], s1 = row_start[v + 1];
    const unsigned short* hp = (const unsigned short*)h;
    float acc[8] = {0.f, 0.f, 0.f, 0.f, 0.f, 0.f, 0.f, 0.f};
    for (int p = s0; p < s1; p++) {   // divergent between halves; exec-mask handles
        int s = csrc[p];
        int c = ccomb[p];
        u16x8 hv = *(const u16x8*)(hp + (size_t)s * 256 + sl * 8);
        f32x4 e0 = *(const f32x4*)(ecomb_l + (size_t)c * 256 + sl * 8);
        f32x4 e1 = *(const f32x4*)(ecomb_l + (size_t)c * 256 + sl * 8 + 4);
        acc[0] += bf2f(hv[0]) + e0.x;
        acc[1] += bf2f(hv[1]) + e0.y;
        acc[2] += bf2f(hv[2]) + e0.z;
        acc[3] += bf2f(hv[3]) + e0.w;
        acc[4] += bf2f(hv[4]) + e1.x;
        acc[5] += bf2f(hv[5]) + e1.y;
        acc[6] += bf2f(hv[6]) + e1.z;
        acc[7] += bf2f(hv[7]) + e1.w;
    }
    u16x8 o;
#pragma unroll
    for (int j = 0; j < 8; j++) o[j] = f2bf(acc[j]);
    *(u16x8*)((unsigned short*)aggrB + (size_t)v * 256 + sl * 8) = o;
}

// C[M,Nn] = act( A[M,K](bf16) * Wt[Nn,K]^T (bf16) + bias )
// 128x128 tile, BK=32, 4 waves, double-buffered LDS with prefetch-before-compute
// (T3-minimum: stage(t+1) issued before ds_read/MFMA(t); ONE barrier per K-step).
// LDS layout XOR-swizzled: slot ^= (r ^ (r>>2)) & 3  (applied on global SOURCE at
// staging per rule 21, same XOR on ds_read address) -> 2-way bank access (free).
// STATS: emit per-block per-column {sum, sumsq} partials (deterministic BN stats).
template<int K, bool RELU, bool OUTBF, bool STATS>
__global__ __launch_bounds__(256) void k_gemm(const __hip_bfloat16* A, const __hip_bfloat16* Wt,
                                              const float* bias, void* out, int Nn,
                                              float* psum, float* psq) {
    __shared__ short lA[2][128 * 32];
    __shared__ short lB[2][128 * 32];
    __shared__ float redS[4][64], redQ[4][64];
    int tid = threadIdx.x;
    int wave = tid >> 6, lane = tid & 63;
    int mBase = blockIdx.x * 128;
    int nBase = blockIdx.y * 128;
    int wr = (wave >> 1) * 64;   // wave row offset in tile
    int wc = (wave & 1) * 64;    // wave col offset in tile
    int lr = lane & 15, lk = lane >> 4;
    const short* Ap = (const short*)A + (size_t)mBase * K;
    const short* Bp = (const short*)Wt + (size_t)nBase * K;
    // staging: chunk = 1KB = 16 rows x 32 cols; lane -> row chunk*16 + lane/4, slot lane&3
    int srow = lane >> 2;
    int sslot = lane & 3;
    f32x4 acc[4][4] = {};
    constexpr int NT = K / 32;

    auto stage = [&](int buf, int k0) {
#pragma unroll
        for (int i = 0; i < 2; i++) {
            int chunk = wave * 2 + i;
            int r = chunk * 16 + srow;
            int scol = (sslot ^ ((r ^ (r >> 2)) & 3)) * 8;   // swizzled source col (shorts)
            __builtin_amdgcn_global_load_lds(
                (const __attribute__((address_space(1))) unsigned int*)(Ap + (size_t)r * K + k0 + scol),
                (__attribute__((address_space(3))) unsigned int*)(&lA[buf][chunk * 512]), 16, 0, 0);
            __builtin_amdgcn_global_load_lds(
                (const __attribute__((address_space(1))) unsigned int*)(Bp + (size_t)r * K + k0 + scol),
                (__attribute__((address_space(3))) unsigned int*)(&lB[buf][chunk * 512]), 16, 0, 0);
        }
    };

    stage(0, 0);
    __syncthreads();   // drain prologue staging

    for (int t = 0; t < NT; t++) {
        int cur = t & 1;
        if (t + 1 < NT) stage(cur ^ 1, (t + 1) * 32);   // prefetch next tile first
        bf16x8 a[4], b[4];
#pragma unroll
        for (int m = 0; m < 4; m++) {
            int r = wr + m * 16 + lr;
            a[m] = *(const bf16x8*)(&lA[cur][r * 32 + ((lk ^ ((r ^ (r >> 2)) & 3)) << 3)]);
        }
#pragma unroll
        for (int n = 0; n < 4; n++) {
            int r = wc + n * 16 + lr;
            b[n] = *(const bf16x8*)(&lB[cur][r * 32 + ((lk ^ ((r ^ (r >> 2)) & 3)) << 3)]);
        }
#pragma unroll
        for (int m = 0; m < 4; m++)
#pragma unroll
            for (int n = 0; n < 4; n++)
                acc[m][n] = __builtin_amdgcn_mfma_f32_16x16x32_bf16(a[m], b[n], acc[m][n], 0, 0, 0);
        __syncthreads();   // drains vmcnt (prefetch done) + protects buf reuse
    }

    float colS[4] = {0.f, 0.f, 0.f, 0.f}, colQ[4] = {0.f, 0.f, 0.f, 0.f};
#pragma unroll
    for (int m = 0; m < 4; m++)
#pragma unroll
        for (int n = 0; n < 4; n++) {
            int cdx = nBase + wc + n * 16 + lr;
            float bi = bias[cdx];
#pragma unroll
            for (int j = 0; j < 4; j++) {
                int r = mBase + wr + m * 16 + lk * 4 + j;
                float v = acc[m][n][j] + bi;
                if (RELU) v = fmaxf(v, 0.f);
                if (OUTBF) ((__hip_bfloat16*)out)[(size_t)r * Nn + cdx] = __float2bfloat16(v);
                else       ((float*)out)[(size_t)r * Nn + cdx] = v;
                if (STATS) { colS[n] += v; colQ[n] += v * v; }
            }
        }

    if (STATS) {
#pragma unroll
        for (int n = 0; n < 4; n++) {
            for (int off = 16; off < 64; off <<= 1) {
                colS[n] += __shfl_xor(colS[n], off);
                colQ[n] += __shfl_xor(colQ[n], off);
            }
        }
        if (lk == 0) {
#pragma unroll
            for (int n = 0; n < 4; n++) {
                redS[wave][n * 16 + lr] = colS[n];
                redQ[wave][n * 16 + lr] = colQ[n];
            }
        }
        __syncthreads();
        if (tid < 128) {
            int c = tid;
            int w0 = (c < 64) ? 0 : 1;
            int cc = c & 63;
            float S = redS[w0][cc] + redS[w0 + 2][cc];
            float Q = redQ[w0][cc] + redQ[w0 + 2][cc];
            psum[(size_t)(nBase + c) * 625 + blockIdx.x] = S;
            psq [(size_t)(nBase + c) * 625 + blockIdx.x] = Q;
        }
    }
}

// one block per column: reduce 625 row-block partials -> scale/shift
__global__ __launch_bounds__(256) void k_bn2(const float* psum, const float* psq,
                                             const float* g, const float* bta, float* stat) {
    __shared__ float s1[256], s2[256];
    int d = blockIdx.x; int t = threadIdx.x;
    float a = 0.f, b = 0.f;
    for (int rb = t; rb < 625; rb += 256) {
        a += psum[(size_t)d * 625 + rb];
        b += psq [(size_t)d * 625 + rb];
    }
    s1[t] = a; s2[t] = b; __syncthreads();
    for (int off = 128; off > 0; off >>= 1) {
        if (t < off) { s1[t] += s1[t + off]; s2[t] += s2[t + off]; }
        __syncthreads();
    }
    if (t == 0) {
        float mean = s1[0] / NN;
        float var = s2[0] / NN - mean * mean;
        float sc = rsqrtf(var + 1e-5f) * g[d];
        stat[d] = sc;
        stat[256 + d] = bta[d] - mean * sc;
    }
}

// vectorized: 4 f32 in, 4 bf16 out per thread; grid covers NN*256/4 threads
__global__ void k_bnapply(const float* h2, const float* stat, __hip_bfloat16* h, int relu) {
    int i = (blockIdx.x * 256 + threadIdx.x) * 4;   // over NN*256
    int d = i & 255;
    f32x4 v = *(const f32x4*)(h2 + i);
    f32x4 sc = *(const f32x4*)(stat + d);
    f32x4 sh = *(const f32x4*)(stat + 256 + d);
    float r0 = v.x * sc.x + sh.x;
    float r1 = v.y * sc.y + sh.y;
    float r2 = v.z * sc.z + sh.z;
    float r3 = v.w * sc.w + sh.w;
    if (relu) {
        r0 = fmaxf(r0, 0.f); r1 = fmaxf(r1, 0.f);
        r2 = fmaxf(r2, 0.f); r3 = fmaxf(r3, 0.f);
    }
    ushort4 o;
    o.x = f2bf(r0); o.y = f2bf(r1); o.z = f2bf(r2); o.w = f2bf(r3);
    *(ushort4*)((unsigned short*)h + i) = o;
}

// ---------------- head ----------------
// reads last-layer h2 (f32) + bnstat directly: BN applied to only the 3200 super-nodes
__global__ __launch_bounds__(128) void k_head(const float* h2, const float* stat,
        const float* HW1, const float* Hb1, const float* HW2, const float* Hb2,
        const float* HW3, const float* Hb3, float* out) {
    __shared__ float row[256], z1[128], z2[128];
    int g = blockIdx.x; int t = threadIdx.x;
    size_t node = (size_t)g * 25 + 24;
    row[t]       = h2[node * 256 + t] * stat[t] + stat[256 + t];
    row[t + 128] = h2[node * 256 + t + 128] * stat[t + 128] + stat[256 + t + 128];
    __syncthreads();
    float acc = Hb1[t];
    for (int k = 0; k < 256; k++) acc += row[k] * HW1[k * 128 + t];
    z1[t] = acc > 0.f ? acc : expm1f(acc);
    __syncthreads();
    acc = Hb2[t];
    for (int k = 0; k < 128; k++) acc += z1[k] * HW2[k * 128 + t];
    z2[t] = acc > 0.f ? acc : expm1f(acc);
    __syncthreads();
    if (t < 2) {
        acc = Hb3[t];
        for (int k = 0; k < 128; k++) acc += z2[k] * HW3[k * 2 + t];
        out[g * 2 + t] = acc;
    }
}

// ---------------- launch ----------------

extern "C" void kernel_launch(void* const* d_in, const int* in_sizes, int n_in,
                              void* d_out, int out_size, void* d_ws, size_t ws_size,
                              hipStream_t stream) {
    const int* x          = (const int*)d_in[0];
    const int* edge_index = (const int*)d_in[1];
    const int* edge_attr  = (const int*)d_in[2];
    const float* node_emb = (const float*)d_in[4];
    const float* ee1 = (const float*)d_in[5];
    const float* ee2 = (const float*)d_in[6];
    const float* ee3 = (const float*)d_in[7];
    const float* W1  = (const float*)d_in[8];
    const float* b1  = (const float*)d_in[9];
    const float* W2  = (const float*)d_in[10];
    const float* b2  = (const float*)d_in[11];
    const float* bng = (const float*)d_in[12];
    const float* bnb = (const float*)d_in[13];
    const float* HW1 = (const float*)d_in[14];
    const float* Hb1 = (const float*)d_in[15];
    const float* HW2 = (const float*)d_in[16];
    const float* Hb2 = (const float*)d_in[17];
    const float* HW3 = (const float*)d_in[18];
    const float* Hb3 = (const float*)d_in[19];
    float* out = (float*)d_out;

    char* ws = (char*)d_ws;
    size_t off = 0;
    auto alloc = [&](size_t bytes) -> char* {
        off = (off + 255) & ~(size_t)255;
        char* p = ws + off;
        off += bytes;
        return p;
    };
    int* deg       = (int*)alloc((size_t)NN * 4);
    int* cursor    = (int*)alloc((size_t)NN * 4);
    int* row_start = (int*)alloc((size_t)(NN + 1) * 4);
    int* blksum    = (int*)alloc((size_t)(NBLK + 1) * 4);
    int* blkoff    = (int*)alloc((size_t)(NBLK + 1) * 4);
    int* eid       = (int*)alloc((size_t)ET * 4);
    int* combo     = (int*)alloc((size_t)ET * 4);
    int* csrc      = (int*)alloc((size_t)ET * 4);
    int* ccomb     = (int*)alloc((size_t)ET * 4);
    float* ecomb   = (float*)alloc((size_t)LL * 300 * 256 * 4);
    __hip_bfloat16* W1t = (__hip_bfloat16*)alloc((size_t)LL * 512 * 256 * 2);
    __hip_bfloat16* W2t = (__hip_bfloat16*)alloc((size_t)LL * 256 * 512 * 2);
    __hip_bfloat16* h    = (__hip_bfloat16*)alloc((size_t)NN * 256 * 2);
    __hip_bfloat16* aggrB = (__hip_bfloat16*)alloc((size_t)NN * 256 * 2);
    __hip_bfloat16* act  = (__hip_bfloat16*)alloc((size_t)NN * 512 * 2);
    float* h2     = (float*)alloc((size_t)NN * 256 * 4);
    float* psum   = (float*)alloc((size_t)256 * 625 * 4);
    float* psq    = (float*)alloc((size_t)256 * 625 * 4);
    float* bnstat = (float*)alloc((size_t)512 * 4);

    hipMemsetAsync(deg, 0, (size_t)NN * 4, stream);
    k_deg<<<(ET + 255) / 256, 256, 0, stream>>>(edge_index, deg);
    k_scan1<<<NBLK, 256, 0, stream>>>(deg, blksum);
    k_scan2<<<1, 512, 0, stream>>>(blksum, blkoff);
    k_scan3<<<NBLK, 256, 0, stream>>>(deg, blkoff, row_start, cursor);
    k_fill<<<(ET + 255) / 256, 256, 0, stream>>>(edge_index, edge_attr, cursor, eid, combo);
    k_sortbkt<<<(NN + 255) / 256, 256, 0, stream>>>(row_start, eid);
    k_remap<<<(ET + 255) / 256, 256, 0, stream>>>(eid, combo, edge_index, csrc, ccomb);
    k_ecomb<<<LL * 300, 256, 0, stream>>>(ee1, ee2, ee3, ecomb);
    k_w1t<<<(LL * 512 * 256 + 255) / 256, 256, 0, stream>>>(W1, W1t);
    k_w2t<<<(LL * 256 * 512 + 255) / 256, 256, 0, stream>>>(W2, W2t);
    k_nodeemb<<<NN, 256, 0, stream>>>(x, node_emb, h);

    for (int l = 0; l < LL; l++) {
        k_aggr<<<NN / 8, 256, 0, stream>>>(h, ecomb + (size_t)l * 300 * 256, row_start,
                                           csrc, ccomb, aggrB);
        k_gemm<256, true, true, false><<<dim3(625, 4), 256, 0, stream>>>(
            aggrB, W1t + (size_t)l * 512 * 256, b1 + l * 512, act, 512, nullptr, nullptr);
        k_gemm<512, false, false, true><<<dim3(625, 2), 256, 0, stream>>>(
            act, W2t + (size_t)l * 256 * 512, b2 + l * 256, h2, 256, psum, psq);
        k_bn2<<<256, 256, 0, stream>>>(psum, psq, bng + l * 256, bnb + l * 256, bnstat);
        if (l < LL - 1)
            k_bnapply<<<NN * 256 / (256 * 4), 256, 0, stream>>>(h2, bnstat, h, 1);
    }

    k_head<<<BB, 128, 0, stream>>>(h2, bnstat, HW1, Hb1, HW2, Hb2, HW3, Hb3, out);
}